// Round 2
// baseline (49.541 us; speedup 1.0000x reference)
//
#include <hip/hip_runtime.h>

#define NN 768
#define WD 256      // ATTN_WIDTH
#define NH 4
#define NEG 0.01f
#define RPB 4       // rows (nodes) per block in k_pre

__device__ __forceinline__ float leaky(float x) { return fmaxf(x, NEG * x); }

// ---- K_pre: per 4 nodes: h = nodes@preW^T; U = h@W1a^T; Vb = h@W1b^T + b1;
//      out_h = nodes@postW^T. Weights read in original layout (row per thread,
//      float4), amortized over RPB rows. ----
__global__ __launch_bounds__(256) void k_pre(const float* __restrict__ nodes,
                                             const float* __restrict__ preW,
                                             const float* __restrict__ postW,
                                             const float* __restrict__ w1,
                                             const float* __restrict__ b1,
                                             float* __restrict__ U,
                                             float* __restrict__ Vb,
                                             float* __restrict__ out_h) {
    __shared__ float nrow[RPB][128];
    __shared__ float hrow[RPB][128];
    const int r0 = blockIdx.x * RPB;
    const int t = threadIdx.x;

    {   // stage RPB node rows
        const float4* src = (const float4*)(nodes + r0 * 128);
        float4* dst = (float4*)&nrow[0][0];
        for (int idx = t; idx < RPB * 32; idx += 256) dst[idx] = src[idx];
    }
    __syncthreads();

    {   // h_proj: thread -> d = t&127; (t>>7) selects row pair {0,1} or {2,3}
        const int d = t & 127;
        const int ra = (t >> 7) * 2, rb = ra + 1;
        const float4* prow = (const float4*)(preW + d * 128);
        float a0 = 0.f, a1 = 0.f;
#pragma unroll
        for (int q = 0; q < 32; ++q) {
            float4 w = prow[q];
            int k = q * 4;
            a0 = fmaf(w.x, nrow[ra][k],     a0); a1 = fmaf(w.x, nrow[rb][k],     a1);
            a0 = fmaf(w.y, nrow[ra][k + 1], a0); a1 = fmaf(w.y, nrow[rb][k + 1], a1);
            a0 = fmaf(w.z, nrow[ra][k + 2], a0); a1 = fmaf(w.z, nrow[rb][k + 2], a1);
            a0 = fmaf(w.w, nrow[ra][k + 3], a0); a1 = fmaf(w.w, nrow[rb][k + 3], a1);
        }
        hrow[ra][d] = a0;
        hrow[rb][d] = a1;
    }
    __syncthreads();

    {   // U / Vb: thread t owns col c = t; reads w1 row t (256 floats)
        float u[RPB] = {}, v[RPB] = {};
        const float4* wrow = (const float4*)(w1 + t * 256);
#pragma unroll 8
        for (int q = 0; q < 32; ++q) {
            float4 w = wrow[q];
            int k = q * 4;
#pragma unroll
            for (int r = 0; r < RPB; ++r) {
                u[r] = fmaf(w.x, hrow[r][k],     u[r]);
                u[r] = fmaf(w.y, hrow[r][k + 1], u[r]);
                u[r] = fmaf(w.z, hrow[r][k + 2], u[r]);
                u[r] = fmaf(w.w, hrow[r][k + 3], u[r]);
            }
        }
#pragma unroll 8
        for (int q = 32; q < 64; ++q) {
            float4 w = wrow[q];
            int k = (q - 32) * 4;
#pragma unroll
            for (int r = 0; r < RPB; ++r) {
                v[r] = fmaf(w.x, hrow[r][k],     v[r]);
                v[r] = fmaf(w.y, hrow[r][k + 1], v[r]);
                v[r] = fmaf(w.z, hrow[r][k + 2], v[r]);
                v[r] = fmaf(w.w, hrow[r][k + 3], v[r]);
            }
        }
        float bb = b1[t];
#pragma unroll
        for (int r = 0; r < RPB; ++r) {
            U[(r0 + r) * 256 + t]  = u[r];
            Vb[(r0 + r) * 256 + t] = v[r] + bb;
        }
    }

    {   // out_h: thread t owns cols t and t+256; postW rows t, t+256
        float o0[RPB] = {}, o1[RPB] = {};
        const float4* p0 = (const float4*)(postW + t * 128);
        const float4* p1 = (const float4*)(postW + (t + 256) * 128);
#pragma unroll 8
        for (int q = 0; q < 32; ++q) {
            float4 wa = p0[q], wb = p1[q];
            int k = q * 4;
#pragma unroll
            for (int r = 0; r < RPB; ++r) {
                o0[r] = fmaf(wa.x, nrow[r][k],     o0[r]);
                o0[r] = fmaf(wa.y, nrow[r][k + 1], o0[r]);
                o0[r] = fmaf(wa.z, nrow[r][k + 2], o0[r]);
                o0[r] = fmaf(wa.w, nrow[r][k + 3], o0[r]);
                o1[r] = fmaf(wb.x, nrow[r][k],     o1[r]);
                o1[r] = fmaf(wb.y, nrow[r][k + 1], o1[r]);
                o1[r] = fmaf(wb.z, nrow[r][k + 2], o1[r]);
                o1[r] = fmaf(wb.w, nrow[r][k + 3], o1[r]);
            }
        }
#pragma unroll
        for (int r = 0; r < RPB; ++r) {
            out_h[(r0 + r) * 512 + t]       = o0[r];
            out_h[(r0 + r) * 512 + 256 + t] = o1[r];
        }
    }
}

// ---- K3: per destination row i: edge list -> scores -> masked softmax -> aggregate ----
__global__ __launch_bounds__(256) void k_attn(const float* __restrict__ adj,
                                              const float* __restrict__ U,
                                              const float* __restrict__ Vb,
                                              const float* __restrict__ out_h,
                                              const float* __restrict__ w2,
                                              const float* __restrict__ b2,
                                              float* __restrict__ out) {
    __shared__ float ulds[256];
    __shared__ float w2l[4 * 256];
    __shared__ int elist[NN];
    __shared__ float sc[NN * NH];               // [e*4 + h]
    __shared__ unsigned long long masks[NN / 64];
    __shared__ int cnt[NN / 64];

    const int i = blockIdx.x, t = threadIdx.x;
    const int lane = t & 63, wv = t >> 6;

    ulds[t] = U[i * 256 + t];
#pragma unroll
    for (int q = 0; q < 4; ++q) w2l[q * 256 + t] = w2[q * 256 + t];

    // ballot-based deterministic edge-list build (12 chunks of 64)
    for (int c = wv; c < NN / 64; c += 4) {
        float a = adj[i * NN + c * 64 + lane];
        unsigned long long m = __ballot(a != 0.0f);
        if (lane == 0) { masks[c] = m; cnt[c] = __popcll(m); }
    }
    __syncthreads();

    int ne = 0;
#pragma unroll
    for (int q = 0; q < NN / 64; ++q) ne += cnt[q];

    for (int c = wv; c < NN / 64; c += 4) {
        int off = 0;
        for (int q = 0; q < c; ++q) off += cnt[q];
        unsigned long long m = masks[c];
        if ((m >> lane) & 1ull) {
            int pos = off + __popcll(m & ((1ull << lane) - 1ull));
            elist[pos] = c * 64 + lane;
        }
    }
    __syncthreads();

    // scores: each wave takes every 4th edge
    for (int e = wv; e < ne; e += 4) {
        int j = elist[e];
        const float* vrow = Vb + j * 256;
        float a0 = 0.f, a1 = 0.f, a2 = 0.f, a3 = 0.f;
#pragma unroll
        for (int q = 0; q < 4; ++q) {
            int w = q * 64 + lane;
            float tv = leaky(ulds[w] + vrow[w]);
            a0 = fmaf(tv, w2l[w],       a0);
            a1 = fmaf(tv, w2l[256 + w], a1);
            a2 = fmaf(tv, w2l[512 + w], a2);
            a3 = fmaf(tv, w2l[768 + w], a3);
        }
#pragma unroll
        for (int off = 32; off; off >>= 1) {
            a0 += __shfl_xor(a0, off);
            a1 += __shfl_xor(a1, off);
            a2 += __shfl_xor(a2, off);
            a3 += __shfl_xor(a3, off);
        }
        if (lane == 0) {
            sc[e * 4 + 0] = leaky(a0 + b2[0]);
            sc[e * 4 + 1] = leaky(a1 + b2[1]);
            sc[e * 4 + 2] = leaky(a2 + b2[2]);
            sc[e * 4 + 3] = leaky(a3 + b2[3]);
        }
    }
    __syncthreads();

    // masked softmax over edges, one wave per head
    {
        int h = wv;
        float m = -INFINITY;
        for (int e = lane; e < ne; e += 64) m = fmaxf(m, sc[e * 4 + h]);
#pragma unroll
        for (int off = 32; off; off >>= 1) m = fmaxf(m, __shfl_xor(m, off));
        float s = 0.f;
        for (int e = lane; e < ne; e += 64) {
            float p = __expf(sc[e * 4 + h] - m);
            sc[e * 4 + h] = p;
            s += p;
        }
#pragma unroll
        for (int off = 32; off; off >>= 1) s += __shfl_xor(s, off);
        float inv = 1.0f / s;
        for (int e = lane; e < ne; e += 64) sc[e * 4 + h] *= inv;
    }
    __syncthreads();

    // aggregate: out[i, c] = sum_e sc[e, c&3] * out_h[j_e, c], c = t and t+256
    float acc0 = 0.f, acc1 = 0.f;
    const int h = t & 3;
    for (int e = 0; e < ne; ++e) {
        int j = elist[e];
        float wgt = sc[e * 4 + h];
        acc0 = fmaf(wgt, out_h[j * 512 + t],       acc0);
        acc1 = fmaf(wgt, out_h[j * 512 + 256 + t], acc1);
    }
    out[i * 512 + t]       = acc0;
    out[i * 512 + 256 + t] = acc1;
}

extern "C" void kernel_launch(void* const* d_in, const int* in_sizes, int n_in,
                              void* d_out, int out_size, void* d_ws, size_t ws_size,
                              hipStream_t stream) {
    const float* nodes = (const float*)d_in[0];
    const float* adj   = (const float*)d_in[1];
    const float* preW  = (const float*)d_in[2];
    const float* postW = (const float*)d_in[3];
    const float* w1    = (const float*)d_in[4];
    const float* b1    = (const float*)d_in[5];
    const float* w2    = (const float*)d_in[6];
    const float* b2    = (const float*)d_in[7];
    float* out = (float*)d_out;

    float* ws = (float*)d_ws;
    float* U     = ws;                 // 768*256
    float* Vb    = U + NN * 256;       // 768*256
    float* out_h = Vb + NN * 256;      // 768*512
    // total: 768*1024 floats = 3 MB

    k_pre<<<dim3(NN / RPB), dim3(256), 0, stream>>>(nodes, preW, postW, w1, b1, U, Vb, out_h);
    k_attn<<<dim3(NN), dim3(256), 0, stream>>>(adj, U, Vb, out_h, w2, b2, out);
}